// Round 9
// baseline (180.486 us; speedup 1.0000x reference)
//
#include <hip/hip_runtime.h>
#include <math.h>

// DCT-II coefficients (fp32 rounding of the float64 reference values).
#define C4 0.3535533906f
#define C1 0.4903926402f
#define C2 0.4619397663f
#define C3 0.4157348062f
#define C5 0.2777851165f
#define C6 0.1913417162f
#define C7 0.0975451610f

// 8-point DCT-II via even/odd butterfly: 36 ops vs 64 for the dense matmul.
__device__ __forceinline__ void dct8(const float* x, float* F) {
  float e0 = x[0] + x[7], e1 = x[1] + x[6], e2 = x[2] + x[5], e3 = x[3] + x[4];
  float o0 = x[0] - x[7], o1 = x[1] - x[6], o2 = x[2] - x[5], o3 = x[3] - x[4];
  float g0 = e0 + e3, g1 = e1 + e2, h0 = e0 - e3, h1 = e1 - e2;
  F[0] = C4 * (g0 + g1);
  F[4] = C4 * (g0 - g1);
  F[2] = fmaf(C2, h0,  C6 * h1);
  F[6] = fmaf(C6, h0, -C2 * h1);
  F[1] = fmaf(C1, o0, fmaf( C3, o1, fmaf( C5, o2,  C7 * o3)));
  F[3] = fmaf(C3, o0, fmaf(-C7, o1, fmaf(-C1, o2, -C5 * o3)));
  F[5] = fmaf(C5, o0, fmaf(-C1, o1, fmaf( C7, o2,  C3 * o3)));
  F[7] = fmaf(C7, o0, fmaf(-C5, o1, fmaf( C3, o2, -C1 * o3)));
}

// 8-point IDCT (transpose of dct8), same butterfly structure.
__device__ __forceinline__ void idct8(const float* F, float* x) {
  float a0 = C4 * (F[0] + F[4]);
  float a1 = C4 * (F[0] - F[4]);
  float b0 = fmaf(C2, F[2],  C6 * F[6]);
  float b1 = fmaf(C6, F[2], -C2 * F[6]);
  float E0 = a0 + b0, E1 = a1 + b1, E2 = a1 - b1, E3 = a0 - b0;
  float O0 = fmaf(C1, F[1], fmaf( C3, F[3], fmaf( C5, F[5],  C7 * F[7])));
  float O1 = fmaf(C3, F[1], fmaf(-C7, F[3], fmaf(-C1, F[5], -C5 * F[7])));
  float O2 = fmaf(C5, F[1], fmaf(-C1, F[3], fmaf( C7, F[5],  C3 * F[7])));
  float O3 = fmaf(C7, F[1], fmaf(-C5, F[3], fmaf( C3, F[5], -C1 * F[7])));
  x[0] = E0 + O0; x[7] = E0 - O0;
  x[1] = E1 + O1; x[6] = E1 - O1;
  x[2] = E2 + O2; x[5] = E2 - O2;
  x[3] = E3 + O3; x[4] = E3 - O3;
}

#define SCR_BLK 68                // floats per 8x8 block (64 + 4 pad -> bank rotate)
#define SCR_CH  (8 * SCR_BLK)     // per channel per wave
#define SCR_WAVE (3 * SCR_CH)

// Wave-synchronous LDS fence (all LDS producer/consumer pairs are same-wave).
#define WAVE_SYNC() do { \
  asm volatile("s_waitcnt lgkmcnt(0)" ::: "memory"); \
  __builtin_amdgcn_sched_barrier(0); } while (0)

__global__ __launch_bounds__(256) void jpeg_fused(
    const float* __restrict__ x,
    const float* __restrict__ qlum,
    const float* __restrict__ qchr,
    float* __restrict__ out)
{
  __shared__ __attribute__((aligned(16))) float scr[4 * SCR_WAVE]; // 26112 B

  const int t  = threadIdx.x;      // 0..255
  const int w  = t >> 6;           // wave 0..3
  const int l  = t & 63;           // lane
  const int wg = blockIdx.x;       // 0..4095
  const int bb = wg >> 5;          // batch 0..127
  const int br = wg & 31;          // block-row 0..31

  const int blk = l >> 3;          // lane's block within the wave's 8-block group
  const int r8  = l & 7;           // row owned (load/A/C/store); column owned (B)
  const int goff = bb * (3 * 65536) + br * (8 * 256) + r8 * 256 + (w * 8 + blk) * 8;

  float* sw  = &scr[w * SCR_WAVE];
  float* sb0 = &sw[0 * SCR_CH + blk * SCR_BLK];
  float* sb1 = &sw[1 * SCR_CH + blk * SCR_BLK];
  float* sb2 = &sw[2 * SCR_CH + blk * SCR_BLK];

  // ---- global loads: lane's 8-float row of its block, all 3 channels
  const float* px = x + goff;
  float4 R0 = *(const float4*)(px);
  float4 R1 = *(const float4*)(px + 4);
  float4 G0 = *(const float4*)(px + 65536);
  float4 G1 = *(const float4*)(px + 65540);
  float4 B0 = *(const float4*)(px + 131072);
  float4 B1 = *(const float4*)(px + 131076);

  // ---- quant tables for this lane's column v=r8: qs = q*1e5 (== q/1e-5 to 1ulp),
  //      rq via v_rcp (1ulp). Replaces 32 IEEE divides (~320 VALU insts) with 32 insts.
  float qs[2][8], rq[2][8];
#pragma unroll
  for (int u = 0; u < 8; ++u) {
    qs[0][u] = qlum[u * 8 + r8] * 1e5f;  rq[0][u] = __builtin_amdgcn_rcpf(qs[0][u]);
    qs[1][u] = qchr[u * 8 + r8] * 1e5f;  rq[1][u] = __builtin_amdgcn_rcpf(qs[1][u]);
  }

  // ---- RGB -> YCbCr rows in registers
  float rr[8]  = {R0.x,R0.y,R0.z,R0.w,R1.x,R1.y,R1.z,R1.w};
  float gr[8]  = {G0.x,G0.y,G0.z,G0.w,G1.x,G1.y,G1.z,G1.w};
  float brw[8] = {B0.x,B0.y,B0.z,B0.w,B1.x,B1.y,B1.z,B1.w};
  float yr[8], cbr[8], crr[8];
#pragma unroll
  for (int n = 0; n < 8; ++n) {
    yr[n]  =  0.299f   * rr[n] + 0.587f    * gr[n] + 0.114f    * brw[n];
    cbr[n] = -0.168736f* rr[n] - 0.331264f * gr[n] + 0.5f      * brw[n] + 128.0f;
    crr[n] =  0.5f     * rr[n] - 0.418688f * gr[n] - 0.081312f * brw[n] + 128.0f;
  }

  // ---- Phase A (x3): row DCT, write transposed scr[blk][8v + r8]
#define PHASE_A(rowarr, sb) do { \
  float Fa[8]; dct8(rowarr, Fa); \
  _Pragma("unroll") \
  for (int v = 0; v < 8; ++v) (sb)[8 * v + r8] = Fa[v]; \
  } while (0)
  PHASE_A(yr,  sb0);
  PHASE_A(cbr, sb1);
  PHASE_A(crr, sb2);
#undef PHASE_A
  WAVE_SYNC();   // A writes -> B reads (cross-lane within 8-lane group, same wave)

  // ---- Phase B (x3): col DCT + quant/dequant + col IDCT; lane owns column v=r8
#define PHASE_B(sb, qsi) do { \
  float tc[8], Fb[8], Zb[8]; \
  *(float4*)&tc[0] = *(const float4*)&(sb)[8 * r8]; \
  *(float4*)&tc[4] = *(const float4*)&(sb)[8 * r8 + 4]; \
  dct8(tc, Fb); \
  _Pragma("unroll") \
  for (int u = 0; u < 8; ++u) \
    Fb[u] = rintf(Fb[u] * rq[qsi][u]) * qs[qsi][u]; \
  idct8(Fb, Zb); \
  _Pragma("unroll") \
  for (int m = 0; m < 8; ++m) (sb)[8 * m + r8] = Zb[m]; /* same-wave DS in-order */ \
  } while (0)
  PHASE_B(sb0, 0);
  PHASE_B(sb1, 1);
  PHASE_B(sb2, 1);
#undef PHASE_B
  WAVE_SYNC();   // B writes -> C reads

  // ---- Phase C (x3): row IDCT back into registers; lane owns row r8 again
#define PHASE_C(sb, outarr) do { \
  float zr[8]; \
  *(float4*)&zr[0] = *(const float4*)&(sb)[8 * r8]; \
  *(float4*)&zr[4] = *(const float4*)&(sb)[8 * r8 + 4]; \
  idct8(zr, outarr); \
  } while (0)
  PHASE_C(sb0, yr);
  PHASE_C(sb1, cbr);
  PHASE_C(sb2, crr);
#undef PHASE_C

  // ---- YCbCr -> RGB, clip, store lane's row
  float ro[8], go[8], bo[8];
#pragma unroll
  for (int j = 0; j < 8; ++j) {
    float y  = yr[j];
    float cb = cbr[j] - 128.0f;
    float cr = crr[j] - 128.0f;
    float r2 = fmaf(1.402f, cr, y);
    float g2 = y - 0.344136f * cb - 0.714136f * cr;
    float b2 = fmaf(1.722f, cb, y);
    ro[j] = fminf(fmaxf(r2, 0.0f), 255.0f);
    go[j] = fminf(fmaxf(g2, 0.0f), 255.0f);
    bo[j] = fminf(fmaxf(b2, 0.0f), 255.0f);
  }
  float* po = out + goff;
  *(float4*)(po)          = (float4){ro[0], ro[1], ro[2], ro[3]};
  *(float4*)(po + 4)      = (float4){ro[4], ro[5], ro[6], ro[7]};
  *(float4*)(po + 65536)  = (float4){go[0], go[1], go[2], go[3]};
  *(float4*)(po + 65540)  = (float4){go[4], go[5], go[6], go[7]};
  *(float4*)(po + 131072) = (float4){bo[0], bo[1], bo[2], bo[3]};
  *(float4*)(po + 131076) = (float4){bo[4], bo[5], bo[6], bo[7]};
}

extern "C" void kernel_launch(void* const* d_in, const int* in_sizes, int n_in,
                              void* d_out, int out_size, void* d_ws, size_t ws_size,
                              hipStream_t stream) {
  (void)in_sizes; (void)n_in; (void)out_size; (void)d_ws; (void)ws_size;
  const float* x    = (const float*)d_in[0];
  const float* qlum = (const float*)d_in[1];
  const float* qchr = (const float*)d_in[2];
  float* out = (float*)d_out;
  // 128 batches * 32 block-rows = 4096 workgroups of 256 threads.
  jpeg_fused<<<dim3(4096), dim3(256), 0, stream>>>(x, qlum, qchr, out);
}